// Round 12
// baseline (2857.404 us; speedup 1.0000x reference)
//
#include <hip/hip_runtime.h>

#define T_ 64

typedef __attribute__((ext_vector_type(4))) float f32x4;
typedef __attribute__((ext_vector_type(8))) short s16x8;

__device__ __forceinline__ unsigned short f2bf(float f) {
  unsigned u = __float_as_uint(f);
  u = (u + 0x7FFFu + ((u >> 16) & 1u)) >> 16;
  return (unsigned short)u;
}
__device__ __forceinline__ float bf2f(unsigned short h) {
  return __uint_as_float(((unsigned)h) << 16);
}
__device__ __forceinline__ float eluf(float x) { return x > 0.f ? x : __expf(x) - 1.f; }
__device__ __forceinline__ float sigmf(float x) { return 1.f / (1.f + __expf(-x)); }
__device__ __forceinline__ float tanh_(float x) {
  float xx = fminf(fmaxf(x, -30.f), 30.f);
  float e = __expf(-2.f * xx);
  return (1.f - e) / (1.f + e);
}
__device__ __forceinline__ float softpf(float x) {
  return x > 20.f ? x : __logf(1.f + __expf(x));
}

// ---- pk layout (u16 offsets) ----
#define OPW1   0        // img1 kt0 only: 13*512 = 6656
#define OPWI   6656     // wi per-gate [3][13][6]: 119808
#define OPWH   126464   // wh per-gate [3][13][6]: 119808
#define OPO1D  246272   // obs1d [13][6]: 39936
#define OPO2   286208   // obs2 [4][6]: 12288
#define OPI2   298496   // img2 KT7 NT13: 46592 (post_head)
#define OPI3   345088   // img3 KT7 NT4: 14336 (post_head)
#define OWIWT  359424   // wi k=192..199 [3][208][8]: 4992
#define OWHWT  364416   // wh k-rem [3][208][8]: 4992
#define OO1DWT 369408   // [208][8]: 1664
#define OI1WT  371072   // img1 k=32..39 [208][8]: 1664
#define OO2WT  372736   // [64][8]: 512
#define PK_U16 373248

#define OFF_PK  26214400
#define OFF_SWZ 26960896

__device__ void pack_mat(int idx, int stride, const float* __restrict__ W,
                         int K, int N, int KT, int NT, unsigned short* __restrict__ dst) {
  int total = KT * NT * 512;
  for (int i = idx; i < total; i += stride) {
    int j = i & 7, l = (i >> 3) & 63, rem = i >> 9;
    int kt = rem % KT, nt = rem / KT;
    int n = nt * 16 + (l & 15), k = kt * 32 + (l >> 4) * 8 + j;
    float v = (k < K && n < N) ? W[(size_t)k * N + n] : 0.f;
    dst[i] = f2bf(v);
  }
}

__device__ void pack_gate(int idx, int stride, const float* __restrict__ W,
                          unsigned short* __restrict__ dst) {
  int total = 3 * 13 * 6 * 512;
  for (int i = idx; i < total; i += stride) {
    int j = i & 7, l = (i >> 3) & 63, rem = i >> 9;
    int kt = rem % 6, rem2 = rem / 6, nt = rem2 % 13, g = rem2 / 13;
    int u = nt * 16 + (l & 15);
    int k = kt * 32 + (l >> 4) * 8 + j;
    float v = (u < 200) ? W[(size_t)k * 600 + g * 200 + u] : 0.f;
    dst[i] = f2bf(v);
  }
}

__global__ void prep_weights(const float* __restrict__ w1, const float* __restrict__ wi,
                             const float* __restrict__ wh, const float* __restrict__ i2,
                             const float* __restrict__ i3, const float* __restrict__ obs1w,
                             const float* __restrict__ o2,
                             unsigned short* __restrict__ pk,
                             unsigned short* __restrict__ swz) {
  int idx = blockIdx.x * blockDim.x + threadIdx.x;
  int stride = gridDim.x * blockDim.x;
  pack_mat(idx, stride, w1, 40, 200, 1, 13, pk + OPW1);
  pack_gate(idx, stride, wi, pk + OPWI);
  pack_gate(idx, stride, wh, pk + OPWH);
  pack_mat(idx, stride, obs1w, 200, 200, 6, 13, pk + OPO1D);
  pack_mat(idx, stride, o2, 200, 60, 6, 4, pk + OPO2);
  pack_mat(idx, stride, i2, 200, 200, 7, 13, pk + OPI2);
  pack_mat(idx, stride, i3, 200, 60, 7, 4, pk + OPI3);
  for (int i = idx; i < 4992; i += stride) {
    int j = i & 7, c = (i >> 3) % 208, g = i / 1664;
    pk[OWIWT + i] = f2bf((c < 200) ? wi[(size_t)(192 + j) * 600 + g * 200 + c] : 0.f);
    pk[OWHWT + i] = f2bf((c < 200) ? wh[(size_t)(192 + j) * 600 + g * 200 + c] : 0.f);
  }
  for (int i = idx; i < 1664; i += stride) {
    int c = i >> 3, j = i & 7;
    pk[OO1DWT + i] = f2bf((c < 200) ? obs1w[(size_t)(192 + j) * 200 + c] : 0.f);
    pk[OI1WT + i]  = f2bf((c < 200) ? w1[(size_t)(32 + j) * 200 + c] : 0.f);
  }
  for (int i = idx; i < 512; i += stride) {
    int c = i >> 3, j = i & 7;
    pk[OO2WT + i] = f2bf((c < 60) ? o2[(size_t)(192 + j) * 60 + c] : 0.f);
  }
  for (int i = idx; i < 212992; i += stride) {
    int j = i & 7, l = (i >> 3) & 63, rem = i >> 9;
    int nt = rem % 13, kc = rem / 13;
    int k = kc * 32 + ((l >> 4) * 8) + j;
    int n = nt * 16 + (l & 15);
    float v = (n < 200) ? obs1w[(size_t)(200 + k) * 200 + n] : 0.0f;
    swz[i] = f2bf(v);
  }
}

// --------------------------------------------------------------------------
// emb_pre = embed @ obs1_w[200:,:] + obs1_b   (validated)
// --------------------------------------------------------------------------
__global__ __launch_bounds__(256) void emb_gemm(const float* __restrict__ embed,
                                                const float* __restrict__ obs1b,
                                                const unsigned short* __restrict__ swz,
                                                unsigned short* __restrict__ emb_pre) {
  __shared__ __align__(16) unsigned short lds_A[64][40];
  int tid = threadIdx.x;
  int lane = tid & 63, w = tid >> 6;
  int R0 = blockIdx.x * 64;
  int tt = R0 >> 10;
  int bb = R0 & 1023;

  f32x4 acc[13];
#pragma unroll
  for (int nt = 0; nt < 13; ++nt) acc[nt] = (f32x4){0.f, 0.f, 0.f, 0.f};

  int i_row = tid >> 2, cg = tid & 3;
  const float* arow = embed + ((size_t)(bb + i_row) * 64 + tt) * 1024 + cg * 8;

  for (int kc = 0; kc < 32; ++kc) {
    __syncthreads();
    {
      const float* p = arow + kc * 32;
      f32x4 a0 = *(const f32x4*)p;
      f32x4 a1 = *(const f32x4*)(p + 4);
      unsigned short* dst = &lds_A[i_row][cg * 8];
      dst[0] = f2bf(a0[0]); dst[1] = f2bf(a0[1]); dst[2] = f2bf(a0[2]); dst[3] = f2bf(a0[3]);
      dst[4] = f2bf(a1[0]); dst[5] = f2bf(a1[1]); dst[6] = f2bf(a1[2]); dst[7] = f2bf(a1[3]);
    }
    __syncthreads();
    s16x8 af = *(const s16x8*)&lds_A[w * 16 + (lane & 15)][(lane >> 4) * 8];
    const unsigned short* bp = swz + (size_t)kc * 6656 + (size_t)lane * 8;
#pragma unroll
    for (int nt = 0; nt < 13; ++nt) {
      s16x8 bfv = *(const s16x8*)(bp + nt * 512);
      acc[nt] = __builtin_amdgcn_mfma_f32_16x16x32_bf16(af, bfv, acc[nt], 0, 0, 0);
    }
  }
  int r0 = R0 + w * 16 + ((lane >> 4) << 2);
  int c0 = lane & 15;
#pragma unroll
  for (int nt = 0; nt < 13; ++nt) {
    int n = nt * 16 + c0;
    if (n < 200) {
      float bv = obs1b[n];
#pragma unroll
      for (int rr = 0; rr < 4; ++rr)
        emb_pre[(size_t)(r0 + rr) * 200 + n] = f2bf(acc[nt][rr] + bv);
    }
  }
}

// --------------------------------------------------------------------------
// scan_v12: 32 blocks x 256 thr (4 waves, v6 shell), M=32 rows/block.
// Streamed quarters of 6 tiles, ring 12, clean FIFO, wh r/z resident.
// --------------------------------------------------------------------------
#define LGKM0  asm volatile("s_waitcnt lgkmcnt(0)" ::: "memory")
#define MEMCLB asm volatile("" ::: "memory")
#define BAR()  __builtin_amdgcn_s_barrier()
#define MFMA16(A, B, C) __builtin_amdgcn_mfma_f32_16x16x32_bf16((A), (B), (C), 0, 0, 0)
#define WV12 asm volatile("s_waitcnt vmcnt(12)" ::: "memory")
#define WV6  asm volatile("s_waitcnt vmcnt(6)" ::: "memory")
#define WV0  asm volatile("s_waitcnt vmcnt(0)" ::: "memory")

typedef __attribute__((address_space(3))) unsigned int u32_lds;
typedef const __attribute__((address_space(1))) unsigned int u32_glb;

__device__ __forceinline__ void gll16(const unsigned short* g, unsigned short* l, int lane) {
  __builtin_amdgcn_global_load_lds((u32_glb*)(g + lane * 8), (u32_lds*)l, 16, 0, 0);
}

// stream quarter address: g = quarter index, kt = tile within
__device__ __forceinline__ unsigned taddr(int w, int g, int kt) {
  if (g >= 16) return OPO1D + (unsigned)((12 * 6 + kt) * 512);        // w0 only
  if (g >= 12 && w != 0) {                                             // w1-3 o1d
    int nt = (w - 1) + 3 * (g - 12);
    return OPO1D + (unsigned)((nt * 6 + kt) * 512);
  }
  int iu = g >> 2, q = g & 3;
  int ug = w + 4 * iu;
  return (q < 3) ? OPWI + (unsigned)(((q * 13 + ug) * 6 + kt) * 512)
                 : OPWH + (unsigned)(((2 * 13 + ug) * 6 + kt) * 512);
}

__device__ __forceinline__ void issue6(int g, unsigned short* ringw,
                                       const unsigned short* pk, int w, int lane) {
#pragma unroll
  for (int kt = 0; kt < 6; ++kt)
    gll16(pk + taddr(w, g, kt), ringw + (((g & 1) * 6 + kt) * 512), lane);
}

// consume quarter B (2 M-halves), optionally reissue B+2
template <int B, bool LAST, bool ISSUE>
__device__ __forceinline__ void consq(const s16x8* A0, const s16x8* A1,
                                      f32x4& ca, f32x4& cb, unsigned short* ringw,
                                      const unsigned short* pk, int w, int lane) {
  if (LAST) { WV0; } else { WV6; }
#pragma unroll
  for (int kt = 0; kt < 6; ++kt) {
    s16x8 Bv = *(const s16x8*)(ringw + (((B & 1) * 6 + kt) * 512) + lane * 8);
    ca = MFMA16(A0[kt], Bv, ca);
    cb = MFMA16(A1[kt], Bv, cb);
  }
  if (ISSUE) {
    LGKM0; MEMCLB;
    issue6(B + 2, ringw, pk, w, lane);
    MEMCLB;
  }
}

__device__ __forceinline__ void res6p(const s16x8* A0, const s16x8* A1,
                                      const s16x8* Wt, f32x4& ca, f32x4& cb) {
#pragma unroll
  for (int kt = 0; kt < 6; ++kt) {
    ca = MFMA16(A0[kt], Wt[kt], ca);
    cb = MFMA16(A1[kt], Wt[kt], cb);
  }
}
__device__ __forceinline__ void rem1p(const s16x8& A60, const s16x8& A61,
                                      const unsigned short* wt, const unsigned short* zb,
                                      bool kg0, f32x4& ca, f32x4& cb) {
  s16x8 W = *(const s16x8*)(kg0 ? wt : zb);
  ca = MFMA16(A60, W, ca);
  cb = MFMA16(A61, W, cb);
}
__device__ __forceinline__ void grustep(const f32x4& rv, const f32x4& zv,
                                        const f32x4& inv, const f32x4& hnv, f32x4& dv) {
#pragma unroll
  for (int rr = 0; rr < 4; ++rr) {
    float r = sigmf(rv[rr]);
    float z = sigmf(zv[rr]);
    float n = tanh_(inv[rr] + r * hnv[rr]);
    dv[rr] = (1.f - z) * n + z * dv[rr];
  }
}

__global__ __launch_bounds__(256, 1) void scan_v12(
    const float* __restrict__ action, const float* __restrict__ eps_post,
    const float* __restrict__ img1_b, const float* __restrict__ gru_bi,
    const float* __restrict__ gru_bh, const float* __restrict__ obs2_b,
    const unsigned short* __restrict__ pk, const unsigned short* __restrict__ emb_pre,
    float* __restrict__ out) {

  __shared__ __align__(16) unsigned short ring[4][12][512];   // 48 KB
  __shared__ __align__(16) unsigned short l_w1[13 * 512];
  __shared__ __align__(16) unsigned short l_o2[24 * 512];
  __shared__ __align__(16) unsigned short l_wiWT[3][208][8];
  __shared__ __align__(16) unsigned short l_whWT[3][208][8];
  __shared__ __align__(16) unsigned short l_o1dWT[208][8];
  __shared__ __align__(16) unsigned short l_i1WT[208][8];
  __shared__ __align__(16) unsigned short l_o2WT[64][8];
  __shared__ __align__(16) unsigned short zblk[8];
  __shared__ __align__(16) unsigned short xoA[28][32][8];
  __shared__ __align__(16) unsigned short dA[28][32][8];
  __shared__ __align__(16) unsigned short sA[8][32][8];
  __shared__ __align__(16) float s_o[60][36];

  const int tid = threadIdx.x, lane = tid & 63, w = tid >> 6;
  const int arow = lane & 15, kg = lane >> 4;
  const bool kg0 = (kg == 0);
  const int b0 = blockIdx.x * 32;
  unsigned short* ringw = &ring[w][0][0];

  // ---------- prologue: LDS ----------
  for (int i = tid; i < 7168; i += 256) { (&xoA[0][0][0])[i] = 0; (&dA[0][0][0])[i] = 0; }
  for (int i = tid; i < 2048; i += 256) (&sA[0][0][0])[i] = 0;
  for (int i = tid; i < 13 * 512; i += 256) l_w1[i] = pk[OPW1 + i];
  for (int i = tid; i < 24 * 512; i += 256) l_o2[i] = pk[OPO2 + i];
  for (int i = tid; i < 4992; i += 256) {
    (&l_wiWT[0][0][0])[i] = pk[OWIWT + i];
    (&l_whWT[0][0][0])[i] = pk[OWHWT + i];
  }
  for (int i = tid; i < 1664; i += 256) {
    (&l_o1dWT[0][0])[i] = pk[OO1DWT + i];
    (&l_i1WT[0][0])[i] = pk[OI1WT + i];
  }
  for (int i = tid; i < 512; i += 256) (&l_o2WT[0][0])[i] = pk[OO2WT + i];
  if (tid < 8) zblk[tid] = 0;

  // ---------- resident wh r,z (up to 8 chunk-sets) ----------
  const int nug = (w == 0) ? 4 : 3;
  s16x8 wB[8][6];
#pragma unroll
  for (int s = 0; s < 8; ++s) {
    int iu = s >> 1, g = s & 1;
    int ug = (iu < nug) ? (w + 4 * iu) : w;
    const unsigned short* base = pk + OPWH + (size_t)((g * 13 + ug) * 6) * 512;
#pragma unroll
    for (int kt = 0; kt < 6; ++kt)
      wB[s][kt] = *(const s16x8*)(base + (size_t)kt * 512 + lane * 8);
  }

  // ---------- biases ----------
  float bs0[4], bs1[4], bi2v[4], bh2v[4], b1v[4];
  int uWT[4];
#pragma unroll
  for (int iu = 0; iu < 4; ++iu) {
    bool vld = (iu < 3 || w == 0);
    int ug = w + 4 * iu;
    int u = ug * 16 + arow;
    uWT[iu] = vld ? u : 0;                 // <= 207
    bool m = vld && (u < 200);
    int uc = m ? u : 0;
    float mm = m ? 1.f : 0.f;
    bs0[iu] = mm * (gru_bi[uc] + gru_bh[uc]);
    bs1[iu] = mm * (gru_bi[200 + uc] + gru_bh[200 + uc]);
    bi2v[iu] = mm * gru_bi[400 + uc];
    bh2v[iu] = mm * gru_bh[400 + uc];
    b1v[iu] = mm * img1_b[uc];
  }
  const int c5 = w * 16 + arow;            // 0..63
  const float b5 = (c5 < 60) ? obs2_b[c5] : 0.f;

  // ---------- aux (t=0) ----------
  unsigned short e16[32];
#pragma unroll
  for (int i = 0; i < 32; ++i) e16[i] = 0;
#pragma unroll
  for (int i = 0; i < 4; ++i) {
    if (i == 0 || w != 0) {
      int nt = (w == 0) ? 12 : ((w - 1) + 3 * i);
      int c = nt * 16 + arow;
      int cc = (c < 200) ? c : 199;
#pragma unroll
      for (int h = 0; h < 2; ++h)
#pragma unroll
        for (int rr = 0; rr < 4; ++rr)
          e16[i * 8 + h * 4 + rr] = __builtin_nontemporal_load(
              &emb_pre[((size_t)(b0 + h * 16 + kg * 4 + rr)) * 200 + cc]);
    }
  }
  float epsv[4];
#pragma unroll
  for (int k2 = 0; k2 < 4; ++k2) {
    int idx = tid + k2 * 256; idx = (idx < 960) ? idx : 959;
    epsv[k2] = __builtin_nontemporal_load(&eps_post[((size_t)(b0 + idx / 30)) * 30 + idx % 30]);
  }
  float act0[2], actn[2];
#pragma unroll
  for (int k2 = 0; k2 < 2; ++k2) {
    int sl = tid + k2 * 256; sl = (sl < 320) ? sl : 319;
    act0[k2] = __builtin_nontemporal_load(&action[((size_t)(b0 + sl / 10) * T_ + 0) * 10 + sl % 10]);
    actn[k2] = __builtin_nontemporal_load(&action[((size_t)(b0 + sl / 10) * T_ + 1) * 10 + sl % 10]);
  }
  f32x4 dv[4][2];
#pragma unroll
  for (int iu = 0; iu < 4; ++iu)
#pragma unroll
    for (int h = 0; h < 2; ++h) dv[iu][h] = (f32x4){0.f, 0.f, 0.f, 0.f};

  __syncthreads();
#pragma unroll
  for (int k2 = 0; k2 < 2; ++k2) {
    int sl = tid + k2 * 256;
    if (sl < 320) {
      int r = sl / 10, kk = sl % 10;
      sA[(30 + kk) >> 3][r][(30 + kk) & 7] = f2bf(act0[k2]);
    }
  }
  issue6(0, ringw, pk, w, lane);
  issue6(1, ringw, pk, w, lane);
  WV0;
  __syncthreads();

  // ---------------- T loop ----------------
  for (int t = 0; t < T_; ++t) {
    // ===== S1: x = elu([stoch|act]@img1 + b1) =====
    {
      s16x8 a00 = *(const s16x8*)&sA[kg][arow][0];
      s16x8 a01 = *(const s16x8*)&sA[kg][16 + arow][0];
      s16x8 a10 = *(const s16x8*)&sA[4 + kg][arow][0];
      s16x8 a11 = *(const s16x8*)&sA[4 + kg][16 + arow][0];
#pragma unroll
      for (int iu = 0; iu < 4; ++iu) {
        if (iu < 3 || w == 0) {
          int nt = (iu < 3) ? (w + 4 * iu) : 12;
          int c = nt * 16 + arow;
          s16x8 B0 = *(const s16x8*)&l_w1[nt * 512 + lane * 8];
          f32x4 xa = {b1v[iu], b1v[iu], b1v[iu], b1v[iu]};
          f32x4 xb = xa;
          xa = MFMA16(a00, B0, xa);
          xb = MFMA16(a01, B0, xb);
          rem1p(a10, a11, &l_i1WT[c][0], zblk, kg0, xa, xb);
          if (c < 200) {
#pragma unroll
            for (int rr = 0; rr < 4; ++rr) {
              xoA[c >> 3][kg * 4 + rr][c & 7] = f2bf(eluf(xa[rr]));
              xoA[c >> 3][16 + kg * 4 + rr][c & 7] = f2bf(eluf(xb[rr]));
            }
          }
        }
      }
    }
    LGKM0; BAR();   // B1: xA ready

    // ===== S2 + GRU (reads old dA) =====
    {
      s16x8 ax0[6], ax1[6], ad0[6], ad1[6];
#pragma unroll
      for (int kt = 0; kt < 6; ++kt) {
        ax0[kt] = *(const s16x8*)&xoA[kt * 4 + kg][arow][0];
        ax1[kt] = *(const s16x8*)&xoA[kt * 4 + kg][16 + arow][0];
        ad0[kt] = *(const s16x8*)&dA[kt * 4 + kg][arow][0];
        ad1[kt] = *(const s16x8*)&dA[kt * 4 + kg][16 + arow][0];
      }
      s16x8 ax60 = *(const s16x8*)&xoA[24 + kg][arow][0];
      s16x8 ax61 = *(const s16x8*)&xoA[24 + kg][16 + arow][0];
      s16x8 ad60 = *(const s16x8*)&dA[24 + kg][arow][0];
      s16x8 ad61 = *(const s16x8*)&dA[24 + kg][16 + arow][0];

#define UG_BODY(IU, LQ3)                                                          \
      {                                                                           \
        const int uc = uWT[IU];                                                   \
        f32x4 rva = {bs0[IU], bs0[IU], bs0[IU], bs0[IU]}, rvb = rva;              \
        consq<IU * 4 + 0, false, true>(ax0, ax1, rva, rvb, ringw, pk, w, lane);   \
        rem1p(ax60, ax61, &l_wiWT[0][uc][0], zblk, kg0, rva, rvb);                \
        res6p(ad0, ad1, wB[IU * 2 + 0], rva, rvb);                                \
        rem1p(ad60, ad61, &l_whWT[0][uc][0], zblk, kg0, rva, rvb);                \
        f32x4 zva = {bs1[IU], bs1[IU], bs1[IU], bs1[IU]}, zvb = zva;              \
        consq<IU * 4 + 1, false, true>(ax0, ax1, zva, zvb, ringw, pk, w, lane);   \
        rem1p(ax60, ax61, &l_wiWT[1][uc][0], zblk, kg0, zva, zvb);                \
        res6p(ad0, ad1, wB[IU * 2 + 1], zva, zvb);                                \
        rem1p(ad60, ad61, &l_whWT[1][uc][0], zblk, kg0, zva, zvb);                \
        f32x4 iva = {bi2v[IU], bi2v[IU], bi2v[IU], bi2v[IU]}, ivb = iva;          \
        consq<IU * 4 + 2, false, true>(ax0, ax1, iva, ivb, ringw, pk, w, lane);   \
        rem1p(ax60, ax61, &l_wiWT[2][uc][0], zblk, kg0, iva, ivb);                \
        f32x4 hva = {bh2v[IU], bh2v[IU], bh2v[IU], bh2v[IU]}, hvb = hva;          \
        consq<IU * 4 + 3, false, LQ3>(ad0, ad1, hva, hvb, ringw, pk, w, lane);    \
        rem1p(ad60, ad61, &l_whWT[2][uc][0], zblk, kg0, hva, hvb);                \
        grustep(rva, zva, iva, hva, dv[IU][0]);                                   \
        grustep(rvb, zvb, ivb, hvb, dv[IU][1]);                                   \
      }
      UG_BODY(0, true)
      UG_BODY(1, true)
      UG_BODY(2, true)
      if (w == 0) { UG_BODY(3, false) }   // B=15: no issue (q17 invalid)
#undef UG_BODY
    }
    LGKM0; BAR();   // B2: all old-dA reads done

    // publish new deter
#pragma unroll
    for (int iu = 0; iu < 4; ++iu) {
      if (iu < 3 || w == 0) {
        int u = (w + 4 * iu) * 16 + arow;
        if (u < 200) {
#pragma unroll
          for (int rr = 0; rr < 4; ++rr) {
            dA[u >> 3][kg * 4 + rr][u & 7] = f2bf(dv[iu][0][rr]);
            dA[u >> 3][16 + kg * 4 + rr][u & 7] = f2bf(dv[iu][1][rr]);
          }
        }
      }
    }
    LGKM0; BAR();   // B3: dA ready

    // ===== S4: o1 = elu(deter@obs1d + emb) =====
    {
      s16x8 ad40[6], ad41[6];
#pragma unroll
      for (int kt = 0; kt < 6; ++kt) {
        ad40[kt] = *(const s16x8*)&dA[kt * 4 + kg][arow][0];
        ad41[kt] = *(const s16x8*)&dA[kt * 4 + kg][16 + arow][0];
      }
      s16x8 ad460 = *(const s16x8*)&dA[24 + kg][arow][0];
      s16x8 ad461 = *(const s16x8*)&dA[24 + kg][16 + arow][0];
      if (w != 0) {
#define O1_BODY(I, LST, ISS)                                                      \
        {                                                                         \
          int c = ((w - 1) + 3 * (I)) * 16 + arow;                                \
          f32x4 oa = {0.f, 0.f, 0.f, 0.f}, ob = oa;                               \
          consq<12 + (I), LST, ISS>(ad40, ad41, oa, ob, ringw, pk, w, lane);      \
          rem1p(ad460, ad461, &l_o1dWT[c][0], zblk, kg0, oa, ob);                 \
          for (int rr = 0; rr < 4; ++rr) {                                        \
            xoA[c >> 3][kg * 4 + rr][c & 7] =                                     \
                f2bf(eluf(oa[rr] + bf2f(e16[(I) * 8 + rr])));                     \
            xoA[c >> 3][16 + kg * 4 + rr][c & 7] =                                \
                f2bf(eluf(ob[rr] + bf2f(e16[(I) * 8 + 4 + rr])));                 \
          }                                                                       \
        }
        O1_BODY(0, false, true)
        O1_BODY(1, false, true)
        O1_BODY(2, false, false)
        O1_BODY(3, true, false)
#undef O1_BODY
      } else {
        int c = 192 + arow;
        f32x4 oa = {0.f, 0.f, 0.f, 0.f}, ob = oa;
        consq<16, true, false>(ad40, ad41, oa, ob, ringw, pk, w, lane);
        rem1p(ad460, ad461, &l_o1dWT[c][0], zblk, kg0, oa, ob);
        if (c < 200) {
#pragma unroll
          for (int rr = 0; rr < 4; ++rr) {
            xoA[c >> 3][kg * 4 + rr][c & 7] = f2bf(eluf(oa[rr] + bf2f(e16[rr])));
            xoA[c >> 3][16 + kg * 4 + rr][c & 7] = f2bf(eluf(ob[rr] + bf2f(e16[4 + rr])));
          }
        }
      }
    }
    LGKM0; BAR();   // B4: o1 ready

    // ===== S5: o = o1@obs2 + b5 =====
    {
      s16x8 a50[6], a51[6];
#pragma unroll
      for (int kt = 0; kt < 6; ++kt) {
        a50[kt] = *(const s16x8*)&xoA[kt * 4 + kg][arow][0];
        a51[kt] = *(const s16x8*)&xoA[kt * 4 + kg][16 + arow][0];
      }
      s16x8 a560 = *(const s16x8*)&xoA[24 + kg][arow][0];
      s16x8 a561 = *(const s16x8*)&xoA[24 + kg][16 + arow][0];
      f32x4 pa = {b5, b5, b5, b5}, pb = pa;
#pragma unroll
      for (int kt = 0; kt < 6; ++kt) {
        s16x8 Bv = *(const s16x8*)&l_o2[(w * 6 + kt) * 512 + lane * 8];
        pa = MFMA16(a50[kt], Bv, pa);
        pb = MFMA16(a51[kt], Bv, pb);
      }
      rem1p(a560, a561, &l_o2WT[c5][0], zblk, kg0, pa, pb);
      if (c5 < 60) {
        *(f32x4*)&s_o[c5][kg * 4] = pa;
        *(f32x4*)&s_o[c5][16 + kg * 4] = pb;
      }
    }
    LGKM0; BAR();   // B5: s_o ready

    // ===== S6: sampling (direct stores) + aux prefetch =====
    {
#pragma unroll
      for (int k2 = 0; k2 < 4; ++k2) {
        int idx = tid + k2 * 256;
        bool v = idx < 960;
        int ic = v ? idx : 959;
        int r = ic / 30, j = ic % 30;
        float qm = s_o[j][r];
        float qs = softpf(s_o[j + 30][r]) + 0.1f;
        float qst = qm + qs * epsv[k2];
        size_t ob = ((size_t)(b0 + r) * T_ + t) * 580;
        if (v) {
          __builtin_nontemporal_store(qm, out + ob + j);
          __builtin_nontemporal_store(qs, out + ob + 30 + j);
          __builtin_nontemporal_store(qst, out + ob + 60 + j);
          sA[j >> 3][r][j & 7] = f2bf(qst);
        }
      }
#pragma unroll
      for (int k2 = 0; k2 < 2; ++k2) {
        int sl = tid + k2 * 256;
        if (sl < 320) {
          int r = sl / 10, kk = sl % 10;
          sA[(30 + kk) >> 3][r][(30 + kk) & 7] = f2bf(actn[k2]);
        }
      }
      int tc = (t + 1 < T_) ? t + 1 : T_ - 1;
      int ta = (t + 2 < T_) ? t + 2 : T_ - 1;
#pragma unroll
      for (int i = 0; i < 4; ++i) {
        if (i == 0 || w != 0) {
          int nt = (w == 0) ? 12 : ((w - 1) + 3 * i);
          int c = nt * 16 + arow;
          int cc = (c < 200) ? c : 199;
#pragma unroll
          for (int h = 0; h < 2; ++h)
#pragma unroll
            for (int rr = 0; rr < 4; ++rr)
              e16[i * 8 + h * 4 + rr] = __builtin_nontemporal_load(
                  &emb_pre[((size_t)tc * 1024 + b0 + h * 16 + kg * 4 + rr) * 200 + cc]);
        }
      }
#pragma unroll
      for (int k2 = 0; k2 < 4; ++k2) {
        int idx = tid + k2 * 256; idx = (idx < 960) ? idx : 959;
        epsv[k2] = __builtin_nontemporal_load(
            &eps_post[((size_t)tc * 1024 + b0 + idx / 30) * 30 + idx % 30]);
      }
#pragma unroll
      for (int k2 = 0; k2 < 2; ++k2) {
        int sl = tid + k2 * 256; sl = (sl < 320) ? sl : 319;
        actn[k2] = __builtin_nontemporal_load(
            &action[((size_t)(b0 + sl / 10) * T_ + ta) * 10 + sl % 10]);
      }
    }
    LGKM0; BAR();   // B6: sA ready

    // ===== S7: deter stores + next-step issue + clean drain =====
#pragma unroll
    for (int iu = 0; iu < 4; ++iu) {
      if (iu < 3 || w == 0) {
        int u = (w + 4 * iu) * 16 + arow;
        if (u < 200) {
#pragma unroll
          for (int h = 0; h < 2; ++h)
#pragma unroll
            for (int rr = 0; rr < 4; ++rr)
              __builtin_nontemporal_store(dv[iu][h][rr],
                  out + ((size_t)(b0 + h * 16 + kg * 4 + rr) * T_ + t) * 580 + 90 + u);
        }
      }
    }
    MEMCLB;
    issue6(0, ringw, pk, w, lane);
    issue6(1, ringw, pk, w, lane);
    WV12;
    MEMCLB;
  }
}

// --------------------------------------------------------------------------
// post_head: prior head (img2->elu->img3), time-parallel; copies deter dup.
// --------------------------------------------------------------------------
__global__ __launch_bounds__(256) void post_head(const float* __restrict__ eps_prior,
                                                 const float* __restrict__ img2_b,
                                                 const float* __restrict__ img3_b,
                                                 const unsigned short* __restrict__ pk,
                                                 float* __restrict__ out) {
  __shared__ __align__(16) unsigned short dAp[4][28][16][8];
  __shared__ __align__(16) unsigned short y1p[4][28][16][8];
  __shared__ __align__(16) float s_p[60][68];
  int b = blockIdx.x;
  int tid = threadIdx.x;
  int lane = tid & 63, w = tid >> 6, arow = lane & 15, kg = lane >> 4;

  for (int i = tid; i < 1536; i += 256) {
    int mt = i / 384, rem = i % 384;
    int gidx = 25 + rem / 128, r2 = (rem % 128) / 8, j = rem & 7;
    dAp[mt][gidx][r2][j] = 0;
    y1p[mt][gidx][r2][j] = 0;
  }
  for (int i = tid; i < 12800; i += 256) {
    int row = i / 200, c = i % 200;
    float v = out[((size_t)(b * 64 + row)) * 580 + 90 + c];
    dAp[row >> 4][c >> 3][row & 15][c & 7] = f2bf(v);
  }
  __syncthreads();

  s16x8 ad[7];
#pragma unroll
  for (int kt = 0; kt < 7; ++kt) ad[kt] = *(const s16x8*)&dAp[w][kt * 4 + kg][arow][0];
#pragma unroll
  for (int nt = 0; nt < 13; ++nt) {
    int col = nt * 16 + arow;
    float bv = (col < 200) ? img2_b[col] : 0.f;
    f32x4 acc = {bv, bv, bv, bv};
#pragma unroll
    for (int kt = 0; kt < 7; ++kt) {
      s16x8 Bv = *(const s16x8*)(pk + OPI2 + (size_t)((nt * 7 + kt) * 512) + lane * 8);
      acc = __builtin_amdgcn_mfma_f32_16x16x32_bf16(ad[kt], Bv, acc, 0, 0, 0);
    }
    if (col < 200) {
#pragma unroll
      for (int rr = 0; rr < 4; ++rr)
        y1p[w][col >> 3][kg * 4 + rr][col & 7] = f2bf(eluf(acc[rr]));
    }
  }
  __syncthreads();

  s16x8 ay[7];
#pragma unroll
  for (int kt = 0; kt < 7; ++kt) ay[kt] = *(const s16x8*)&y1p[w][kt * 4 + kg][arow][0];
#pragma unroll
  for (int nt = 0; nt < 4; ++nt) {
    int col = nt * 16 + arow;
    float bv = (col < 60) ? img3_b[col] : 0.f;
    f32x4 acc = {bv, bv, bv, bv};
#pragma unroll
    for (int kt = 0; kt < 7; ++kt) {
      s16x8 Bv = *(const s16x8*)(pk + OPI3 + (size_t)((nt * 7 + kt) * 512) + lane * 8);
      acc = __builtin_amdgcn_mfma_f32_16x16x32_bf16(ay[kt], Bv, acc, 0, 0, 0);
    }
    if (col < 60) {
#pragma unroll
      for (int rr = 0; rr < 4; ++rr) s_p[col][w * 16 + kg * 4 + rr] = acc[rr];
    }
  }
  __syncthreads();

  for (int i = tid; i < 1920; i += 256) {
    int row = i / 30, j = i % 30;
    float pm = s_p[j][row];
    float ps = softpf(s_p[j + 30][row]) + 0.1f;
    float pst = pm + ps * eps_prior[((size_t)row * 1024 + b) * 30 + j];
    size_t ob = ((size_t)b * 64 + row) * 580;
    out[ob + 290 + j] = pm;
    out[ob + 320 + j] = ps;
    out[ob + 350 + j] = pst;
  }
  for (int i = tid; i < 6400; i += 256) {
    int row = i / 100, c2 = i % 100;
    size_t ob = ((size_t)b * 64 + row) * 580;
    *(float2*)&out[ob + 380 + c2 * 2] = *(const float2*)&out[ob + 90 + c2 * 2];
  }
}

extern "C" void kernel_launch(void* const* d_in, const int* in_sizes, int n_in,
                              void* d_out, int out_size, void* d_ws, size_t ws_size,
                              hipStream_t stream) {
  const float* embed    = (const float*)d_in[0];
  const float* action   = (const float*)d_in[1];
  const float* eps_post = (const float*)d_in[2];
  const float* eps_prior= (const float*)d_in[3];
  const float* img1_w   = (const float*)d_in[4];
  const float* img1_b   = (const float*)d_in[5];
  const float* gru_wi   = (const float*)d_in[6];
  const float* gru_wh   = (const float*)d_in[7];
  const float* gru_bi   = (const float*)d_in[8];
  const float* gru_bh   = (const float*)d_in[9];
  const float* img2_w   = (const float*)d_in[10];
  const float* img2_b   = (const float*)d_in[11];
  const float* img3_w   = (const float*)d_in[12];
  const float* img3_b   = (const float*)d_in[13];
  const float* obs1_w   = (const float*)d_in[14];
  const float* obs1_b   = (const float*)d_in[15];
  const float* obs2_w   = (const float*)d_in[16];
  const float* obs2_b   = (const float*)d_in[17];

  char* ws = (char*)d_ws;
  unsigned short* emb_pre = (unsigned short*)ws;
  unsigned short* pkw     = (unsigned short*)(ws + OFF_PK);
  unsigned short* swz     = (unsigned short*)(ws + OFF_SWZ);
  float* outp = (float*)d_out;

  prep_weights<<<256, 256, 0, stream>>>(img1_w, gru_wi, gru_wh, img2_w, img3_w,
                                        obs1_w, obs2_w, pkw, swz);
  emb_gemm<<<1024, 256, 0, stream>>>(embed, obs1_b, swz, emb_pre);
  scan_v12<<<32, 256, 0, stream>>>(action, eps_post, img1_b, gru_bi, gru_bh,
                                   obs2_b, pkw, emb_pre, outp);
  post_head<<<1024, 256, 0, stream>>>(eps_prior, img2_b, img3_b, pkw, outp);
}